// Round 1
// baseline (32.665 us; speedup 1.0000x reference)
//
#include <hip/hip_runtime.h>

constexpr int M_NODES = 4096;
constexpr int T_IN    = 24;
constexpr int HIDN    = 64;
constexpr int HOR     = 10;

// One wave (64 lanes). Computes mean of y0, then integrates the scalar ODE
// with torchdiffeq's 3/8-rule RK4, writing cumulative shifts c[0..H-1] to ws.
__global__ __launch_bounds__(64) void ode_scalar_kernel(
    const float* __restrict__ x,
    const float* __restrict__ W1, const float* __restrict__ b1,
    const float* __restrict__ W2, const float* __restrict__ b2,
    const float* __restrict__ W3, const float* __restrict__ b3,
    float* __restrict__ c_out)
{
    const int lane = threadIdx.x;

    // --- mean of x[0, :, T_IN-1] over M_NODES rows ---
    float s = 0.f;
    #pragma unroll
    for (int k = 0; k < M_NODES / 64; ++k)
        s += x[(k * 64 + lane) * T_IN + (T_IN - 1)];
    #pragma unroll
    for (int off = 32; off; off >>= 1) s += __shfl_down(s, off, 64);
    float mu = __shfl(s, 0, 64) / (float)M_NODES;

    // --- per-lane weights: lane j owns hidden unit j ---
    const float w1  = W1[lane];
    const float bb1 = b1[lane];
    const float bb2 = b2[lane];
    const float w3  = W3[lane];
    const float bb3 = b3[0];
    float w2[HIDN];                      // column j of W2 (W2[i][j] for all i)
    #pragma unroll
    for (int i = 0; i < HIDN; ++i) w2[i] = W2[i * HIDN + lane];

    __shared__ float h1s[HIDN];

    auto feval = [&](float y) -> float {
        float h1 = tanhf(y * w1 + bb1);        // (1,64) first layer, lane j = unit j
        __syncthreads();                        // WAR guard vs previous reads
        h1s[lane] = h1;
        __syncthreads();
        // second layer: lane j computes h2[j] = sum_i h1[i] * W2[i][j] + b2[j]
        float a0 = 0.f, a1 = 0.f, a2 = 0.f, a3 = 0.f;  // split chains for ILP
        #pragma unroll
        for (int i = 0; i < HIDN; i += 4) {
            a0 += h1s[i + 0] * w2[i + 0];
            a1 += h1s[i + 1] * w2[i + 1];
            a2 += h1s[i + 2] * w2[i + 2];
            a3 += h1s[i + 3] * w2[i + 3];
        }
        float h2 = tanhf((a0 + a1) + (a2 + a3) + bb2);
        // third layer: scalar = sum_j h2[j] * W3[j] + b3
        float p = h2 * w3;
        #pragma unroll
        for (int off = 32; off; off >>= 1) p += __shfl_down(p, off, 64);
        return __shfl(p, 0, 64) + bb3;
    };

    const float DT = (float)HOR / (float)(HOR - 1);   // 10/9
    float c = 0.f;
    if (lane == 0) c_out[0] = 0.f;
    for (int t = 1; t < HOR; ++t) {
        float k1 = feval(mu);
        float k2 = feval(mu + DT * k1 * (1.f / 3.f));
        float k3 = feval(mu + DT * (k2 - k1 * (1.f / 3.f)));
        float k4 = feval(mu + DT * (k1 - k2 + k3));
        float d  = DT * (k1 + 3.f * k2 + 3.f * k3 + k4) * 0.125f;
        mu += d;
        c  += d;
        if (lane == 0) c_out[t] = c;
    }
}

// out[n*HOR + h] = y0[n] + c[h]
__global__ __launch_bounds__(256) void write_out_kernel(
    const float* __restrict__ x,
    const float* __restrict__ c,
    float* __restrict__ out)
{
    int idx = blockIdx.x * blockDim.x + threadIdx.x;
    if (idx >= M_NODES * HOR) return;
    int n = idx / HOR;
    int h = idx - n * HOR;
    out[idx] = x[n * T_IN + (T_IN - 1)] + c[h];
}

extern "C" void kernel_launch(void* const* d_in, const int* in_sizes, int n_in,
                              void* d_out, int out_size, void* d_ws, size_t ws_size,
                              hipStream_t stream) {
    const float* x  = (const float*)d_in[0];
    const float* W1 = (const float*)d_in[1];
    const float* b1 = (const float*)d_in[2];
    const float* W2 = (const float*)d_in[3];
    const float* b2 = (const float*)d_in[4];
    const float* W3 = (const float*)d_in[5];
    const float* b3 = (const float*)d_in[6];
    float* out = (float*)d_out;
    float* c   = (float*)d_ws;   // HOR floats of scratch

    ode_scalar_kernel<<<1, 64, 0, stream>>>(x, W1, b1, W2, b2, W3, b3, c);

    constexpr int TOTAL = M_NODES * HOR;
    write_out_kernel<<<(TOTAL + 255) / 256, 256, 0, stream>>>(x, c, out);
}

// Round 2
// 24.410 us; speedup vs baseline: 1.3382x; 1.3382x over previous
//
#include <hip/hip_runtime.h>

constexpr int M_NODES = 4096;
constexpr int T_IN    = 24;
constexpr int HIDN    = 64;
constexpr int HOR     = 10;

// tanh(x) = 1 - 2/(exp(2x)+1), with native v_exp_f32 / v_rcp_f32.
// |err| ~1e-7 rel — tolerance here is 7.2e-2, so this is free accuracy-wise.
__device__ __forceinline__ float fast_tanh(float x) {
    float e = __builtin_amdgcn_exp2f(x * 2.8853900817779268f);  // exp(2x) = 2^(2*log2e*x)
    return 1.f - 2.f * __builtin_amdgcn_rcpf(e + 1.f);
}

// DPP full-wave (64-lane) sum -> uniform scalar via readlane(63).
// rocPRIM-style: row_shr 1,2,4,8 then row_bcast15 (rows 1,3) + row_bcast31 (rows 2,3).
template<int CTRL, int ROW_MASK>
__device__ __forceinline__ float dpp_add(float v) {
    int t = __builtin_amdgcn_update_dpp(0, __float_as_int(v), CTRL, ROW_MASK, 0xf, true);
    return v + __int_as_float(t);
}
__device__ __forceinline__ float wave_allsum(float v) {
    v = dpp_add<0x111, 0xf>(v);   // row_shr:1
    v = dpp_add<0x112, 0xf>(v);   // row_shr:2
    v = dpp_add<0x114, 0xf>(v);   // row_shr:4
    v = dpp_add<0x118, 0xf>(v);   // row_shr:8  -> lane15 of each row = row sum
    v = dpp_add<0x142, 0xa>(v);   // row_bcast:15 into rows 1,3
    v = dpp_add<0x143, 0xc>(v);   // row_bcast:31 into rows 2,3 -> lane63 = total
    return __int_as_float(__builtin_amdgcn_readlane(__float_as_int(v), 63));
}

__global__ __launch_bounds__(256, 1) void fused_gode_kernel(
    const float* __restrict__ x,
    const float* __restrict__ W1, const float* __restrict__ b1,
    const float* __restrict__ W2, const float* __restrict__ b2,
    const float* __restrict__ W3, const float* __restrict__ b3,
    float* __restrict__ out)
{
    const int tid  = threadIdx.x;
    const int lane = tid & 63;
    const int wid  = tid >> 6;

    __shared__ float y0s[M_NODES];            // 16 KB: y0 cached for write phase
    __shared__ float psum[256];
    __shared__ __align__(16) float h1s[HIDN];
    __shared__ float cs[HOR];

    // ---- phase 1: all 256 threads load y0 and produce partial sums ----
    float msum = 0.f;
    #pragma unroll
    for (int k = 0; k < M_NODES / 256; ++k) {
        int n = tid + 256 * k;
        float v = x[n * T_IN + (T_IN - 1)];
        y0s[n] = v;
        msum += v;
    }
    psum[tid] = msum;
    __syncthreads();

    // ---- phase 2: wave 0 runs the scalar ODE ----
    if (wid == 0) {
        float s = psum[lane] + psum[lane + 64] + psum[lane + 128] + psum[lane + 192];
        float mu = wave_allsum(s) * (1.0f / (float)M_NODES);

        const float w1  = W1[lane];
        const float bb1 = b1[lane];
        const float bb2 = b2[lane];
        const float w3  = W3[lane];
        const float bb3 = b3[0];
        float w2[HIDN];                        // column `lane` of W2
        #pragma unroll
        for (int i = 0; i < HIDN; ++i) w2[i] = W2[i * HIDN + lane];

        auto feval = [&](float y) -> float {
            float h1 = fast_tanh(fmaf(y, w1, bb1));
            h1s[lane] = h1;                            // wave-synchronous LDS
            __builtin_amdgcn_wave_barrier();
            const float4* h4 = (const float4*)h1s;
            float a0 = 0.f, a1 = 0.f, a2 = 0.f, a3 = 0.f;
            float a4 = 0.f, a5 = 0.f, a6 = 0.f, a7 = 0.f;
            #pragma unroll
            for (int i = 0; i < 8; ++i) {
                float4 u = h4[2 * i], v = h4[2 * i + 1];
                a0 = fmaf(u.x, w2[8 * i + 0], a0);
                a1 = fmaf(u.y, w2[8 * i + 1], a1);
                a2 = fmaf(u.z, w2[8 * i + 2], a2);
                a3 = fmaf(u.w, w2[8 * i + 3], a3);
                a4 = fmaf(v.x, w2[8 * i + 4], a4);
                a5 = fmaf(v.y, w2[8 * i + 5], a5);
                a6 = fmaf(v.z, w2[8 * i + 6], a6);
                a7 = fmaf(v.w, w2[8 * i + 7], a7);
            }
            float h2 = fast_tanh(((a0 + a1) + (a2 + a3)) + ((a4 + a5) + (a6 + a7)) + bb2);
            __builtin_amdgcn_wave_barrier();            // keep next h1s write after reads
            return wave_allsum(h2 * w3) + bb3;
        };

        const float DT = (float)HOR / (float)(HOR - 1);   // 10/9
        float c = 0.f;
        if (lane == 0) cs[0] = 0.f;
        for (int t = 1; t < HOR; ++t) {
            float k1 = feval(mu);
            float k2 = feval(mu + DT * k1 * (1.f / 3.f));
            float k3 = feval(mu + DT * (k2 - k1 * (1.f / 3.f)));
            float k4 = feval(mu + DT * (k1 - k2 + k3));
            float d  = DT * (k1 + 3.f * k2 + 3.f * k3 + k4) * 0.125f;
            mu += d;
            c  += d;
            if (lane == 0) cs[t] = c;
        }
    }
    __syncthreads();

    // ---- phase 3: all threads write out[n*HOR + h] = y0[n] + c[h], float4 coalesced ----
    float4* out4 = (float4*)out;
    constexpr int NV4 = M_NODES * HOR / 4;    // 10240
    #pragma unroll
    for (int k = 0; k < NV4 / 256; ++k) {     // 40 iters
        int idx = tid + 256 * k;
        int e = idx * 4;
        int n = e / 10;
        int h = e - n * 10;
        float4 v;
        v.x = y0s[n] + cs[h]; if (++h == 10) { h = 0; ++n; }
        v.y = y0s[n] + cs[h]; if (++h == 10) { h = 0; ++n; }
        v.z = y0s[n] + cs[h]; if (++h == 10) { h = 0; ++n; }
        v.w = y0s[n] + cs[h];
        out4[idx] = v;
    }
}

extern "C" void kernel_launch(void* const* d_in, const int* in_sizes, int n_in,
                              void* d_out, int out_size, void* d_ws, size_t ws_size,
                              hipStream_t stream) {
    const float* x  = (const float*)d_in[0];
    const float* W1 = (const float*)d_in[1];
    const float* b1 = (const float*)d_in[2];
    const float* W2 = (const float*)d_in[3];
    const float* b2 = (const float*)d_in[4];
    const float* W3 = (const float*)d_in[5];
    const float* b3 = (const float*)d_in[6];
    float* out = (float*)d_out;

    fused_gode_kernel<<<1, 256, 0, stream>>>(x, W1, b1, W2, b2, W3, b3, out);
}

// Round 3
// 19.467 us; speedup vs baseline: 1.6780x; 1.2539x over previous
//
#include <hip/hip_runtime.h>

typedef _Float16 half2_t __attribute__((ext_vector_type(2)));
typedef _Float16 half8_t __attribute__((ext_vector_type(8)));

constexpr int M_NODES = 4096;
constexpr int T_IN    = 24;
constexpr int HIDN    = 64;
constexpr int HOR     = 10;

// tanh(x) = 1 - 2/(exp(2x)+1) with native v_exp_f32 / v_rcp_f32 (~1e-7 rel err).
__device__ __forceinline__ float fast_tanh(float x) {
    float e = __builtin_amdgcn_exp2f(x * 2.8853900817779268f);  // 2^(2*log2e*x)
    return 1.f - 2.f * __builtin_amdgcn_rcpf(e + 1.f);
}

__device__ __forceinline__ float fdot2f16(half2_t a, half2_t b, float c) {
#if __has_builtin(__builtin_amdgcn_fdot2)
    return __builtin_amdgcn_fdot2(a, b, c, false);
#else
    return fmaf((float)a[0], (float)b[0], fmaf((float)a[1], (float)b[1], c));
#endif
}

// DPP full-wave (64-lane) sum -> uniform scalar via readlane(63).
template<int CTRL, int ROW_MASK>
__device__ __forceinline__ float dpp_add(float v) {
    int t = __builtin_amdgcn_update_dpp(0, __float_as_int(v), CTRL, ROW_MASK, 0xf, true);
    return v + __int_as_float(t);
}
__device__ __forceinline__ float wave_allsum(float v) {
    v = dpp_add<0x111, 0xf>(v);   // row_shr:1
    v = dpp_add<0x112, 0xf>(v);   // row_shr:2
    v = dpp_add<0x114, 0xf>(v);   // row_shr:4
    v = dpp_add<0x118, 0xf>(v);   // row_shr:8
    v = dpp_add<0x142, 0xa>(v);   // row_bcast:15 -> rows 1,3
    v = dpp_add<0x143, 0xc>(v);   // row_bcast:31 -> rows 2,3; lane63 = total
    return __int_as_float(__builtin_amdgcn_readlane(__float_as_int(v), 63));
}

__global__ __launch_bounds__(256, 1) void fused_gode_kernel(
    const float* __restrict__ x,
    const float* __restrict__ W1, const float* __restrict__ b1,
    const float* __restrict__ W2, const float* __restrict__ b2,
    const float* __restrict__ W3, const float* __restrict__ b3,
    float* __restrict__ out)
{
    const int tid  = threadIdx.x;
    const int lane = tid & 63;
    const int wid  = tid >> 6;

    __shared__ float y0s[M_NODES];                 // y0 cache for write phase
    __shared__ float psum[256];
    __shared__ __align__(16) _Float16 h1h[HIDN];   // h1 broadcast buffer (f16)
    __shared__ float cs[HOR];

    // ---- wave 0: issue all weight loads FIRST (latency hides under phase 1) ----
    float w2f[HIDN];
    float w1 = 0.f, bb1 = 0.f, bb2 = 0.f, w3 = 0.f, bb3 = 0.f;
    if (wid == 0) {
        #pragma unroll
        for (int i = 0; i < HIDN; ++i) w2f[i] = W2[i * HIDN + lane];  // column `lane`
        w1  = W1[lane];
        bb1 = b1[lane];
        bb2 = b2[lane];
        w3  = W3[lane];
        bb3 = b3[0];
    }

    // ---- phase 1: all 256 threads gather y0 and produce partial sums ----
    float msum = 0.f;
    #pragma unroll
    for (int k = 0; k < M_NODES / 256; ++k) {
        int n = tid + 256 * k;
        float v = x[n * T_IN + (T_IN - 1)];
        y0s[n] = v;
        msum += v;
    }
    psum[tid] = msum;
    __syncthreads();

    // ---- phase 2: wave 0 runs the scalar ODE ----
    if (wid == 0) {
        float s = psum[lane] + psum[lane + 64] + psum[lane + 128] + psum[lane + 192];
        float mu = wave_allsum(s) * (1.0f / (float)M_NODES);

        // pack W2 column into 32 half2 registers
        half2_t w2h[HIDN / 2];
        #pragma unroll
        for (int i = 0; i < HIDN; i += 2)
            w2h[i / 2] = half2_t{(_Float16)w2f[i], (_Float16)w2f[i + 1]};

        // feval on the pre-activation argument arg = y*w1 + b1 (per lane)
        auto feval = [&](float arg) -> float {
            float h1 = fast_tanh(arg);
            h1h[lane] = (_Float16)h1;              // wave-synchronous LDS (in-order pipe)
            __builtin_amdgcn_wave_barrier();
            const half8_t* hv = (const half8_t*)h1h;
            float acc[8];
            #pragma unroll
            for (int r = 0; r < 8; ++r) {
                half8_t u = hv[r];                 // uniform addr -> broadcast, no conflict
                half2_t p0{u[0], u[1]}, p1{u[2], u[3]}, p2{u[4], u[5]}, p3{u[6], u[7]};
                float a = fdot2f16(p0, w2h[4 * r + 0], 0.f);
                a = fdot2f16(p1, w2h[4 * r + 1], a);
                a = fdot2f16(p2, w2h[4 * r + 2], a);
                acc[r] = fdot2f16(p3, w2h[4 * r + 3], a);
            }
            float h2 = fast_tanh((((acc[0] + acc[1]) + (acc[2] + acc[3])) +
                                  ((acc[4] + acc[5]) + (acc[6] + acc[7]))) + bb2);
            __builtin_amdgcn_wave_barrier();       // keep next write after reads
            return wave_allsum(h2 * w3) + bb3;
        };

        const float DT  = (float)HOR / (float)(HOR - 1);   // 10/9
        const float dw  = DT * w1;
        const float dw3 = (DT * (1.f / 3.f)) * w1;

        float c = 0.f;
        if (lane == 0) cs[0] = 0.f;
        for (int t = 1; t < HOR; ++t) {
            float base = fmaf(mu, w1, bb1);
            float k1 = feval(base);
            float k2 = feval(fmaf(k1, dw3, base));
            float k3 = feval(fmaf(k2, dw, fmaf(k1, -dw3, base)));
            float k4 = feval(fmaf(k3, dw, fmaf(k1 - k2, dw, base)));
            float d  = DT * (k1 + 3.f * k2 + 3.f * k3 + k4) * 0.125f;
            mu += d;
            c  += d;
            if (lane == 0) cs[t] = c;
        }
    }
    __syncthreads();

    // ---- phase 3: out[n*HOR + h] = y0[n] + c[h], float4 coalesced ----
    float4* out4 = (float4*)out;
    constexpr int NV4 = M_NODES * HOR / 4;    // 10240
    #pragma unroll
    for (int k = 0; k < NV4 / 256; ++k) {     // 40 iters
        int idx = tid + 256 * k;
        int e = idx * 4;
        int n = e / 10;
        int h = e - n * 10;
        float4 v;
        v.x = y0s[n] + cs[h]; if (++h == 10) { h = 0; ++n; }
        v.y = y0s[n] + cs[h]; if (++h == 10) { h = 0; ++n; }
        v.z = y0s[n] + cs[h]; if (++h == 10) { h = 0; ++n; }
        v.w = y0s[n] + cs[h];
        out4[idx] = v;
    }
}

extern "C" void kernel_launch(void* const* d_in, const int* in_sizes, int n_in,
                              void* d_out, int out_size, void* d_ws, size_t ws_size,
                              hipStream_t stream) {
    const float* x  = (const float*)d_in[0];
    const float* W1 = (const float*)d_in[1];
    const float* b1 = (const float*)d_in[2];
    const float* W2 = (const float*)d_in[3];
    const float* b2 = (const float*)d_in[4];
    const float* W3 = (const float*)d_in[5];
    const float* b3 = (const float*)d_in[6];
    float* out = (float*)d_out;

    fused_gode_kernel<<<1, 256, 0, stream>>>(x, W1, b1, W2, b2, W3, b3, out);
}